// Round 10
// baseline (83.706 us; speedup 1.0000x reference)
//
#include <hip/hip_runtime.h>
#include <math.h>

// IMPACT modality argmin — R10: 32-lane-per-query main (2 queries/wave,
// 65536 waves, ~9 VMEM instrs/wave vs 27 in R9) + R7 s4 descriptor table +
// counting sort + XCD-chunked blocks. Latency-bound regime (HBM <2 TB/s at
// FETCH ~75MB all rounds): fewer dependent memory ops per query x more
// waves = more outstanding-load capacity.
//
// Pipeline (all on `stream`):
//   1. memsetAsync: hist + flag_cnt = 0
//   2. impact_hist (int4): hist[item]++
//   3. impact_scan_part: per-256-chunk exclusive scan -> cursor, sums -> bsum
//   4. impact_scatter (fused top-scan): s4[pos] = {q, uid, iid, nb} sorted by
//      item -> ONE 16B broadcast load per query in main; same-item adjacent.
//   5. impact_main: 32-lane group = 1 query. u-row = ONE float4 instr (512B);
//      each v-row = ONE instr (and one 64-lane instr covers row m for both
//      queries of the wave). Rows in 3 batches of 4 (16 v-regs in flight,
//      VGPR ~50 < 64 cliff). Partials to wave-private LDS [12][36] (144B row
//      pitch, 16B-aligned -> ds_read_b128; writes full bank permutation,
//      reads <=2-way = free; no block barrier). Lane-m serial sum over 32
//      partials, one 16-lane argmin butterfly (best, idx, second).
//      gap < TAU -> flag.
//   6. impact_refine: flagged queries recomputed in exact f64 (absmax 0.0
//      rounds 1-9).

#define M_TOT 14
#define CDIM 128
#define TAU 0.05f
#define XSTR 36        // xpose row stride in words (144 B, 16B-aligned)

// ---------------- prep: counting sort by item ----------------
__global__ void impact_hist(const int* __restrict__ item_ids,
                            int* __restrict__ hist, int B) {
    int i = blockIdx.x * blockDim.x + threadIdx.x;
    int i4 = i * 4;
    if (i4 + 3 < B) {
        int4 v = *(const int4*)(item_ids + i4);
        atomicAdd(&hist[v.x], 1);
        atomicAdd(&hist[v.y], 1);
        atomicAdd(&hist[v.z], 1);
        atomicAdd(&hist[v.w], 1);
    } else {
        for (int k = i4; k < B; ++k) atomicAdd(&hist[item_ids[k]], 1);
    }
}

__global__ __launch_bounds__(256) void impact_scan_part(
    const int* __restrict__ hist, int* __restrict__ cursor,
    int* __restrict__ bsum, int n) {
    __shared__ int sd[256];
    int t = threadIdx.x;
    int k = blockIdx.x * 256 + t;
    int v = (k < n) ? hist[k] : 0;
    sd[t] = v;
    __syncthreads();
#pragma unroll
    for (int off = 1; off < 256; off <<= 1) {
        int x = (t >= off) ? sd[t - off] : 0;
        __syncthreads();
        sd[t] += x;
        __syncthreads();
    }
    if (k < n) cursor[k] = sd[t] - v;          // exclusive within chunk
    if (t == 255) bsum[blockIdx.x] = sd[255];  // chunk total
}

// scatter with fused top-level scan of bsum (nblk <= 128)
__global__ __launch_bounds__(256) void impact_scatter(
    const int* __restrict__ item_ids,
    const int* __restrict__ user_ids,
    const int* __restrict__ nb_mod,
    int* __restrict__ cursor,
    const int* __restrict__ bsum, int nblk,
    int4* __restrict__ s4, int B)
{
    __shared__ int bo[128];
    int t = threadIdx.x;
    int v0 = 0;
    if (t < 128) {
        v0 = (t < nblk) ? bsum[t] : 0;
        bo[t] = v0;
    }
    __syncthreads();
#pragma unroll
    for (int off = 1; off < 128; off <<= 1) {
        int x = (t < 128 && t >= off) ? bo[t - off] : 0;
        __syncthreads();
        if (t < 128) bo[t] += x;
        __syncthreads();
    }
    int ex = (t < 128) ? bo[t] - v0 : 0;       // exclusive chunk offset
    __syncthreads();
    if (t < 128) bo[t] = ex;
    __syncthreads();

    int i = blockIdx.x * blockDim.x + t;
    int i4 = i * 4;
    if (i4 + 3 < B) {
        int4 it = *(const int4*)(item_ids + i4);
        int4 us = *(const int4*)(user_ids + i4);
        int n0 = nb_mod[it.x], n1 = nb_mod[it.y];
        int n2 = nb_mod[it.z], n3 = nb_mod[it.w];
        int p0 = atomicAdd(&cursor[it.x], 1) + bo[it.x >> 8];
        int p1 = atomicAdd(&cursor[it.y], 1) + bo[it.y >> 8];
        int p2 = atomicAdd(&cursor[it.z], 1) + bo[it.z >> 8];
        int p3 = atomicAdd(&cursor[it.w], 1) + bo[it.w >> 8];
        s4[p0] = make_int4(i4,     us.x, it.x, n0);
        s4[p1] = make_int4(i4 + 1, us.y, it.y, n1);
        s4[p2] = make_int4(i4 + 2, us.z, it.z, n2);
        s4[p3] = make_int4(i4 + 3, us.w, it.w, n3);
    } else {
        for (int k = i4; k < B; ++k) {
            int it = item_ids[k];
            int p = atomicAdd(&cursor[it], 1) + bo[it >> 8];
            s4[p] = make_int4(k, user_ids[k], it, nb_mod[it]);
        }
    }
}

// ---------------- main kernel ----------------
__global__ __launch_bounds__(256) void impact_main(
    const int4* __restrict__ s4,           // sorted (q,uid,iid,nb); may be null
    const int* __restrict__ user_ids,
    const int* __restrict__ item_ids,
    const int* __restrict__ nb_mod,
    const float* __restrict__ users_emb,   // [USER_N, 128]
    const float* __restrict__ item_emb,    // [ITEM_N*14, 128]
    float* __restrict__ out,
    int* __restrict__ flag_cnt,
    int* __restrict__ flag_list,
    int B)
{
    // per-group transpose scratch: 8 groups x 12 rows x stride 36 words
    __shared__ float xpose[8 * 12 * XSTR];   // 13824 B

    // chunked XCD mapping: consecutive sorted blocks -> same XCD L2
    int p = blockIdx.x;
    int lb = p;
    if ((gridDim.x & 7) == 0) {
        int cpx = gridDim.x >> 3;
        lb = (p & 7) * cpx + (p >> 3);
    }

    int grp = threadIdx.x >> 5;        // 32-lane group = 1 query (0..7)
    int l   = threadIdx.x & 31;
    int qi = lb * 8 + grp;             // 8 queries per block

    bool vq = qi < B;
    int4 cur;
    if (s4) {
        cur = vq ? s4[qi] : make_int4(0, 0, 0, 2);
    } else {
        int qq = vq ? qi : 0;
        int ii = item_ids[qq];
        cur = make_int4(qq, user_ids[qq], ii, nb_mod[ii]);
    }
    int q = cur.x, uid = cur.y, iid = cur.z, nb = cur.w;

    // full 512B user row in ONE 32-lane float4 instruction
    const float4* urow = (const float4*)(users_emb + (size_t)uid * CDIM);
    float4 u = urow[l];

    const float4* vbase =
        (const float4*)(item_emb + ((size_t)iid * M_TOT + 1) * CDIM);
    float* X = xpose + grp * 12 * XSTR;

    // 12 rows in 3 batches of 4; each row = ONE 32-lane load (both wave
    // halves = both queries covered by the same instruction)
#pragma unroll
    for (int mb = 0; mb < 12; mb += 4) {
        float4 a[4];
#pragma unroll
        for (int j = 0; j < 4; ++j) {
            int m = mb + j;
            if (m < nb) a[j] = vbase[(size_t)m * (CDIM / 4) + l];
        }
#pragma unroll
        for (int j = 0; j < 4; ++j) {
            int m = mb + j;
            if (m < nb) {
                float d0 = u.x - a[j].x, d1 = u.y - a[j].y;
                float d2 = u.z - a[j].z, d3 = u.w - a[j].w;
                X[m * XSTR + l] = (d0 * d0 + d1 * d1) + (d2 * d2 + d3 * d3);
            }
        }
    }

    // X is wave-private: program order + compiler lgkmcnt orders the RAW
    // within the wave; no block barrier (validated R7-R9, absmax 0.0).

    // lane m sums row m's 32 partials as 8x ds_read_b128 (stride 144B:
    // m-pairs (m, m+8) 2-way alias = free; lanes >=12 broadcast row 0)
    int lm = (l < 12) ? l : 0;
    const float4* R4 = (const float4*)(X + lm * XSTR);
    float t0 = 0.f, t1 = 0.f, t2 = 0.f, t3 = 0.f;
#pragma unroll
    for (int r = 0; r < 2; ++r) {
        float4 a = R4[r * 4 + 0], b = R4[r * 4 + 1];
        float4 c = R4[r * 4 + 2], d = R4[r * 4 + 3];
        t0 += a.x + a.y + a.z + a.w;
        t1 += b.x + b.y + b.z + b.w;
        t2 += c.x + c.y + c.z + c.w;
        t3 += d.x + d.y + d.z + d.w;
    }
    float s = (t0 + t1) + (t2 + t3);
    if (l >= nb || l >= 12) s = INFINITY;

    // 16-lane argmin butterfly (closed under lanes 0-15 of each half;
    // lanes 16-31 compute junk harmlessly). Tracks (best, idx, second).
    float b1 = s, b2 = INFINITY;
    int i1 = (l & 15) + 1;
#pragma unroll
    for (int off = 1; off < 16; off <<= 1) {
        float ob1 = __shfl_xor(b1, off);
        float ob2 = __shfl_xor(b2, off);
        int   oi1 = __shfl_xor(i1, off);
        float lo = fminf(b1, ob1);
        float hi = fmaxf(b1, ob1);
        if (ob1 < b1 || (ob1 == b1 && oi1 < i1)) i1 = oi1;
        b1 = lo;
        b2 = fminf(fminf(b2, ob2), hi);
    }

    if (l == 0 && vq) {
        out[q] = (float)(i1 - 1) / (float)(nb - 1) + 1.0f;
        if (b2 - b1 < TAU && flag_cnt) {
            int pos = atomicAdd(flag_cnt, 1);
            flag_list[pos] = q;
        }
    }
}

// ---------------- exact f64 refinement (rare) ----------------
__global__ __launch_bounds__(256) void impact_refine(
    const int* __restrict__ user_ids,
    const int* __restrict__ item_ids,
    const float* __restrict__ users_emb,
    const float* __restrict__ item_emb,
    const int* __restrict__ nb_mod,
    const int* __restrict__ flag_cnt,
    const int* __restrict__ flag_list,
    float* __restrict__ out)
{
    int cnt = *flag_cnt;
    int ngrp = (gridDim.x * blockDim.x) >> 4;
    int gid = (blockIdx.x * blockDim.x + threadIdx.x) >> 4;
    int l = threadIdx.x & 15;

    for (int i = gid; i < cnt; i += ngrp) {
        int q = flag_list[i];
        int uid = user_ids[q];
        int iid = item_ids[q];
        int nb  = nb_mod[iid];

        const float4* urow = (const float4*)(users_emb + (size_t)uid * CDIM);
        float4 u0 = urow[l];
        float4 u1 = urow[l + 16];

        double best = 1e300;
        int bidx = 1;
        const float4* ibase =
            (const float4*)(item_emb + ((size_t)iid * M_TOT + 1) * CDIM);

        for (int m = 1; m <= nb; ++m) {
            const float4* vr = ibase + (size_t)(m - 1) * (CDIM / 4);
            float4 v0 = vr[l];
            float4 v1 = vr[l + 16];
            float d;
            double sd = 0.0;
            d = u0.x - v0.x; sd += (double)d * d;
            d = u0.y - v0.y; sd += (double)d * d;
            d = u0.z - v0.z; sd += (double)d * d;
            d = u0.w - v0.w; sd += (double)d * d;
            d = u1.x - v1.x; sd += (double)d * d;
            d = u1.y - v1.y; sd += (double)d * d;
            d = u1.z - v1.z; sd += (double)d * d;
            d = u1.w - v1.w; sd += (double)d * d;
            sd += __shfl_xor(sd, 1);
            sd += __shfl_xor(sd, 2);
            sd += __shfl_xor(sd, 4);
            sd += __shfl_xor(sd, 8);
            if (sd < best) { best = sd; bidx = m; }
        }
        if (l == 0)
            out[q] = (float)(bidx - 1) / (float)(nb - 1) + 1.0f;
    }
}

extern "C" void kernel_launch(void* const* d_in, const int* in_sizes, int n_in,
                              void* d_out, int out_size, void* d_ws, size_t ws_size,
                              hipStream_t stream) {
    // inputs: 0 user_ids, 1 item_ids, 2 concept_ids (unused),
    //         3 users_emb_weight, 4 item_resp_emb_weight,
    //         5 mask (unused; nb_modalities carries the same info), 6 nb_modalities
    const int*   user_ids  = (const int*)d_in[0];
    const int*   item_ids  = (const int*)d_in[1];
    const float* users_emb = (const float*)d_in[3];
    const float* item_emb  = (const float*)d_in[4];
    const int*   nb_mod    = (const int*)d_in[6];
    float* out = (float*)d_out;

    int B = in_sizes[0];
    int n_items = in_sizes[6];
    int nblk = (n_items + 255) >> 8;   // scan chunks of 256

    // ws layout: s4[B] int4 | hist[n] | flag_cnt[1] pad[3] | cursor[n]
    //            | bsum[128] | flag_list[B]
    size_t need = (size_t)B * 16 + ((size_t)n_items * 2 + 4 + 128 + (size_t)B) * 4;
    int4* s4       = (int4*)d_ws;
    int* hist      = (int*)(s4 + B);
    int* flag_cnt  = hist + n_items;
    int* cursor    = flag_cnt + 4;
    int* bsum      = cursor + n_items;
    int* flag_list = bsum + 128;

    bool sorted = (ws_size >= need) && (nblk <= 128);
    if (sorted) {
        hipMemsetAsync(hist, 0, ((size_t)n_items + 4) * sizeof(int), stream);
        impact_hist<<<(B / 4 + 255) / 256, 256, 0, stream>>>(item_ids, hist, B);
        impact_scan_part<<<nblk, 256, 0, stream>>>(hist, cursor, bsum, n_items);
        impact_scatter<<<(B / 4 + 255) / 256, 256, 0, stream>>>(
            item_ids, user_ids, nb_mod, cursor, bsum, nblk, s4, B);
    }

    int grid = (B + 7) / 8;            // 8 queries per 256-thread block
    impact_main<<<grid, 256, 0, stream>>>(
        sorted ? s4 : nullptr, user_ids, item_ids, nb_mod,
        users_emb, item_emb, out,
        sorted ? flag_cnt : nullptr, sorted ? flag_list : nullptr, B);

    if (sorted)
        impact_refine<<<64, 256, 0, stream>>>(
            user_ids, item_ids, users_emb, item_emb, nb_mod,
            flag_cnt, flag_list, out);
}

// Round 11
// 69.986 us; speedup vs baseline: 1.1960x; 1.1960x over previous
//
#include <hip/hip_runtime.h>
#include <math.h>

// IMPACT modality argmin — R11: R9 structure with batch-12 main (issue ALL
// valid v-row loads before consuming any). A/B of concurrency source:
// 4 waves/SIMD x ~25 loads in flight (this) vs R9's 8 waves x ~9.
// NO __launch_bounds__ min-waves clamp (R8 lesson: cap -> scratch spill,
// WRITE 4->102 MB). Everything else identical to R9 (71.0 us best).
//
// Pipeline (all on `stream`):
//   1. memsetAsync: hist + flag_cnt = 0
//   2. impact_hist (int4): hist[item]++
//   3. impact_scan_part: per-256-chunk exclusive scan -> cursor, sums -> bsum
//   4. impact_scatter (fused top-scan): s4[pos] = {q, uid, iid, nb} sorted by
//      item -> ONE 16B broadcast load per query; same-item queries adjacent.
//   5. impact_main: 16-lane group = 1 query (32768 waves). desc -> issue u +
//      ALL <=12 v-rows (predicated, ~16 loads avg in flight) -> consume in
//      issue order (vmcnt retires in order -> pipelined). Partials to
//      wave-private LDS (stride 68 words, 16B-aligned -> ds_read_b128
//      epilogue; writes 2-way banks = free; no block barrier). Lane-m serial
//      sum, one 16-lane argmin butterfly (best, idx, second). gap<TAU -> flag.
//   6. impact_refine: flagged queries recomputed in exact f64 (absmax 0.0
//      rounds 1-10).

#define M_TOT 14
#define CDIM 128
#define TAU 0.05f
#define XSTR 68        // xpose row stride in words (272 B, 16B-aligned)

// ---------------- prep: counting sort by item ----------------
__global__ void impact_hist(const int* __restrict__ item_ids,
                            int* __restrict__ hist, int B) {
    int i = blockIdx.x * blockDim.x + threadIdx.x;
    int i4 = i * 4;
    if (i4 + 3 < B) {
        int4 v = *(const int4*)(item_ids + i4);
        atomicAdd(&hist[v.x], 1);
        atomicAdd(&hist[v.y], 1);
        atomicAdd(&hist[v.z], 1);
        atomicAdd(&hist[v.w], 1);
    } else {
        for (int k = i4; k < B; ++k) atomicAdd(&hist[item_ids[k]], 1);
    }
}

__global__ __launch_bounds__(256) void impact_scan_part(
    const int* __restrict__ hist, int* __restrict__ cursor,
    int* __restrict__ bsum, int n) {
    __shared__ int sd[256];
    int t = threadIdx.x;
    int k = blockIdx.x * 256 + t;
    int v = (k < n) ? hist[k] : 0;
    sd[t] = v;
    __syncthreads();
#pragma unroll
    for (int off = 1; off < 256; off <<= 1) {
        int x = (t >= off) ? sd[t - off] : 0;
        __syncthreads();
        sd[t] += x;
        __syncthreads();
    }
    if (k < n) cursor[k] = sd[t] - v;          // exclusive within chunk
    if (t == 255) bsum[blockIdx.x] = sd[255];  // chunk total
}

// scatter with fused top-level scan of bsum (nblk <= 128)
__global__ __launch_bounds__(256) void impact_scatter(
    const int* __restrict__ item_ids,
    const int* __restrict__ user_ids,
    const int* __restrict__ nb_mod,
    int* __restrict__ cursor,
    const int* __restrict__ bsum, int nblk,
    int4* __restrict__ s4, int B)
{
    __shared__ int bo[128];
    int t = threadIdx.x;
    int v0 = 0;
    if (t < 128) {
        v0 = (t < nblk) ? bsum[t] : 0;
        bo[t] = v0;
    }
    __syncthreads();
#pragma unroll
    for (int off = 1; off < 128; off <<= 1) {
        int x = (t < 128 && t >= off) ? bo[t - off] : 0;
        __syncthreads();
        if (t < 128) bo[t] += x;
        __syncthreads();
    }
    int ex = (t < 128) ? bo[t] - v0 : 0;       // exclusive chunk offset
    __syncthreads();
    if (t < 128) bo[t] = ex;
    __syncthreads();

    int i = blockIdx.x * blockDim.x + t;
    int i4 = i * 4;
    if (i4 + 3 < B) {
        int4 it = *(const int4*)(item_ids + i4);
        int4 us = *(const int4*)(user_ids + i4);
        int n0 = nb_mod[it.x], n1 = nb_mod[it.y];
        int n2 = nb_mod[it.z], n3 = nb_mod[it.w];
        int p0 = atomicAdd(&cursor[it.x], 1) + bo[it.x >> 8];
        int p1 = atomicAdd(&cursor[it.y], 1) + bo[it.y >> 8];
        int p2 = atomicAdd(&cursor[it.z], 1) + bo[it.z >> 8];
        int p3 = atomicAdd(&cursor[it.w], 1) + bo[it.w >> 8];
        s4[p0] = make_int4(i4,     us.x, it.x, n0);
        s4[p1] = make_int4(i4 + 1, us.y, it.y, n1);
        s4[p2] = make_int4(i4 + 2, us.z, it.z, n2);
        s4[p3] = make_int4(i4 + 3, us.w, it.w, n3);
    } else {
        for (int k = i4; k < B; ++k) {
            int it = item_ids[k];
            int p = atomicAdd(&cursor[it], 1) + bo[it >> 8];
            s4[p] = make_int4(k, user_ids[k], it, nb_mod[it]);
        }
    }
}

// ---------------- main kernel ----------------
__global__ void impact_main(
    const int4* __restrict__ s4,           // sorted (q,uid,iid,nb); may be null
    const int* __restrict__ user_ids,
    const int* __restrict__ item_ids,
    const int* __restrict__ nb_mod,
    const float* __restrict__ users_emb,   // [USER_N, 128]
    const float* __restrict__ item_emb,    // [ITEM_N*14, 128]
    float* __restrict__ out,
    int* __restrict__ flag_cnt,
    int* __restrict__ flag_list,
    int B)
{
    // wave-private transpose scratch: 12 rows x 64 lanes, stride 68 words
    __shared__ float xpose[4 * 12 * XSTR];

    // chunked XCD mapping: consecutive sorted blocks -> same XCD L2
    int p = blockIdx.x;
    int lb = p;
    if ((gridDim.x & 7) == 0) {
        int cpx = gridDim.x >> 3;
        lb = (p & 7) * cpx + (p >> 3);
    }

    int w = threadIdx.x >> 6;          // wave 0..3
    int g = (threadIdx.x >> 4) & 3;    // 16-lane group in wave
    int l = threadIdx.x & 15;
    int qi = lb * 16 + w * 4 + g;      // 16 queries per block

    bool vq = qi < B;
    int4 cur;
    if (s4) {
        cur = vq ? s4[qi] : make_int4(0, 0, 0, 2);
    } else {
        int qq = vq ? qi : 0;
        int ii = item_ids[qq];
        cur = make_int4(qq, user_ids[qq], ii, nb_mod[ii]);
    }
    int q = cur.x, uid = cur.y, iid = cur.z, nb = cur.w;

    const float4* urow = (const float4*)(users_emb + (size_t)uid * CDIM);
    float4 u0 = urow[l];
    float4 u1 = urow[l + 16];
    const float4* vbase =
        (const float4*)(item_emb + ((size_t)iid * M_TOT + 1) * CDIM);
    float* X = xpose + w * 12 * XSTR;

    // batch-12: issue ALL valid row loads (u + up to 24 v-loads in flight),
    // then consume in issue order -- vmcnt retires in order, so consumption
    // pipelines against outstanding loads. ~120 VGPR, no launch_bounds cap.
    float4 a[12], b[12];
#pragma unroll
    for (int m = 0; m < 12; ++m) {
        if (m < nb) {
            const float4* vr = vbase + (size_t)m * (CDIM / 4);
            a[m] = vr[l];
            b[m] = vr[l + 16];
        }
    }
#pragma unroll
    for (int m = 0; m < 12; ++m) {
        if (m < nb) {
            float d0 = u0.x - a[m].x, d1 = u0.y - a[m].y;
            float d2 = u0.z - a[m].z, d3 = u0.w - a[m].w;
            float d4 = u1.x - b[m].x, d5 = u1.y - b[m].y;
            float d6 = u1.z - b[m].z, d7 = u1.w - b[m].w;
            X[m * XSTR + g * 16 + l] =
                ((d0 * d0 + d1 * d1) + (d2 * d2 + d3 * d3))
              + ((d4 * d4 + d5 * d5) + (d6 * d6 + d7 * d7));
        }
    }

    // X region is wave-private: program order + compiler lgkmcnt orders the
    // RAW within the wave; no block barrier (validated R7-R10, absmax 0.0).

    // lane m reads row m's 16 partials as 4x ds_read_b128, serial f32 sum
    int lm = (l < 12) ? l : 0;
    const float4* R4 = (const float4*)(xpose + w * 12 * XSTR + lm * XSTR + g * 16);
    float4 r0 = R4[0], r1 = R4[1], r2 = R4[2], r3 = R4[3];
    float t0 = r0.x + r0.y + r0.z + r0.w;
    float t1 = r1.x + r1.y + r1.z + r1.w;
    float t2 = r2.x + r2.y + r2.z + r2.w;
    float t3 = r3.x + r3.y + r3.z + r3.w;
    float s = (t0 + t1) + (t2 + t3);
    if (l >= nb) s = INFINITY;

    // 16-lane argmin butterfly tracking (best, idx, second-best)
    float b1 = s, b2 = INFINITY;
    int i1 = l + 1;
#pragma unroll
    for (int off = 1; off < 16; off <<= 1) {
        float ob1 = __shfl_xor(b1, off);
        float ob2 = __shfl_xor(b2, off);
        int   oi1 = __shfl_xor(i1, off);
        float lo = fminf(b1, ob1);
        float hi = fmaxf(b1, ob1);
        if (ob1 < b1 || (ob1 == b1 && oi1 < i1)) i1 = oi1;
        b1 = lo;
        b2 = fminf(fminf(b2, ob2), hi);
    }

    if (l == 0 && vq) {
        out[q] = (float)(i1 - 1) / (float)(nb - 1) + 1.0f;
        if (b2 - b1 < TAU && flag_cnt) {
            int pos = atomicAdd(flag_cnt, 1);
            flag_list[pos] = q;
        }
    }
}

// ---------------- exact f64 refinement (rare) ----------------
__global__ __launch_bounds__(256) void impact_refine(
    const int* __restrict__ user_ids,
    const int* __restrict__ item_ids,
    const float* __restrict__ users_emb,
    const float* __restrict__ item_emb,
    const int* __restrict__ nb_mod,
    const int* __restrict__ flag_cnt,
    const int* __restrict__ flag_list,
    float* __restrict__ out)
{
    int cnt = *flag_cnt;
    int ngrp = (gridDim.x * blockDim.x) >> 4;
    int gid = (blockIdx.x * blockDim.x + threadIdx.x) >> 4;
    int l = threadIdx.x & 15;

    for (int i = gid; i < cnt; i += ngrp) {
        int q = flag_list[i];
        int uid = user_ids[q];
        int iid = item_ids[q];
        int nb  = nb_mod[iid];

        const float4* urow = (const float4*)(users_emb + (size_t)uid * CDIM);
        float4 u0 = urow[l];
        float4 u1 = urow[l + 16];

        double best = 1e300;
        int bidx = 1;
        const float4* ibase =
            (const float4*)(item_emb + ((size_t)iid * M_TOT + 1) * CDIM);

        for (int m = 1; m <= nb; ++m) {
            const float4* vr = ibase + (size_t)(m - 1) * (CDIM / 4);
            float4 v0 = vr[l];
            float4 v1 = vr[l + 16];
            float d;
            double sd = 0.0;
            d = u0.x - v0.x; sd += (double)d * d;
            d = u0.y - v0.y; sd += (double)d * d;
            d = u0.z - v0.z; sd += (double)d * d;
            d = u0.w - v0.w; sd += (double)d * d;
            d = u1.x - v1.x; sd += (double)d * d;
            d = u1.y - v1.y; sd += (double)d * d;
            d = u1.z - v1.z; sd += (double)d * d;
            d = u1.w - v1.w; sd += (double)d * d;
            sd += __shfl_xor(sd, 1);
            sd += __shfl_xor(sd, 2);
            sd += __shfl_xor(sd, 4);
            sd += __shfl_xor(sd, 8);
            if (sd < best) { best = sd; bidx = m; }
        }
        if (l == 0)
            out[q] = (float)(bidx - 1) / (float)(nb - 1) + 1.0f;
    }
}

extern "C" void kernel_launch(void* const* d_in, const int* in_sizes, int n_in,
                              void* d_out, int out_size, void* d_ws, size_t ws_size,
                              hipStream_t stream) {
    // inputs: 0 user_ids, 1 item_ids, 2 concept_ids (unused),
    //         3 users_emb_weight, 4 item_resp_emb_weight,
    //         5 mask (unused; nb_modalities carries the same info), 6 nb_modalities
    const int*   user_ids  = (const int*)d_in[0];
    const int*   item_ids  = (const int*)d_in[1];
    const float* users_emb = (const float*)d_in[3];
    const float* item_emb  = (const float*)d_in[4];
    const int*   nb_mod    = (const int*)d_in[6];
    float* out = (float*)d_out;

    int B = in_sizes[0];
    int n_items = in_sizes[6];
    int nblk = (n_items + 255) >> 8;   // scan chunks of 256

    // ws layout: s4[B] int4 | hist[n] | flag_cnt[1] pad[3] | cursor[n]
    //            | bsum[128] | flag_list[B]
    size_t need = (size_t)B * 16 + ((size_t)n_items * 2 + 4 + 128 + (size_t)B) * 4;
    int4* s4       = (int4*)d_ws;
    int* hist      = (int*)(s4 + B);
    int* flag_cnt  = hist + n_items;
    int* cursor    = flag_cnt + 4;
    int* bsum      = cursor + n_items;
    int* flag_list = bsum + 128;

    bool sorted = (ws_size >= need) && (nblk <= 128);
    if (sorted) {
        hipMemsetAsync(hist, 0, ((size_t)n_items + 4) * sizeof(int), stream);
        impact_hist<<<(B / 4 + 255) / 256, 256, 0, stream>>>(item_ids, hist, B);
        impact_scan_part<<<nblk, 256, 0, stream>>>(hist, cursor, bsum, n_items);
        impact_scatter<<<(B / 4 + 255) / 256, 256, 0, stream>>>(
            item_ids, user_ids, nb_mod, cursor, bsum, nblk, s4, B);
    }

    int grid = (B + 15) / 16;          // 16 queries per 256-thread block
    impact_main<<<grid, 256, 0, stream>>>(
        sorted ? s4 : nullptr, user_ids, item_ids, nb_mod,
        users_emb, item_emb, out,
        sorted ? flag_cnt : nullptr, sorted ? flag_list : nullptr, B);

    if (sorted)
        impact_refine<<<24, 256, 0, stream>>>(
            user_ids, item_ids, users_emb, item_emb, nb_mod,
            flag_cnt, flag_list, out);
}

// Round 12
// 58.663 us; speedup vs baseline: 1.4269x; 1.1930x over previous
//
#include <hip/hip_runtime.h>
#include <math.h>

// IMPACT modality argmin — R12: R9/R11 best structure + wave-uniform
// batch-skip (nb avg 7 of 12: stop issuing dead rows' instructions) +
// INLINE f64 near-tie resolution (refine kernel, flag buffers deleted).
//
// Pipeline (all on `stream`):
//   1. memsetAsync: hist = 0
//   2. impact_hist (int4): hist[item]++
//   3. impact_scan_part: per-256-chunk exclusive scan -> cursor, sums -> bsum
//   4. impact_scatter (fused top-scan): s4[pos] = {q, uid, iid, nb} sorted by
//      item -> ONE 16B broadcast load per query; same-item queries adjacent.
//   5. impact_main: 16-lane group = 1 query (32768 waves, ~8 waves/SIMD).
//      Rows in batches of 4 (8 loads in flight before use). Batches 1,2
//      guarded by wave-uniform nbw>4 / nbw>8 (sorted adjacency -> groups
//      share nb -> cheap branches; kills ~25% dead-row issue cost).
//      Partials to wave-private LDS (stride 68 words, ds_read_b128 epilogue,
//      no block barrier). One 16-lane argmin butterfly (best, idx, second).
//      gap < TAU (group-uniform) -> inline exact f64 re-solve (R1's proven
//      reduction, v-rows L1-hot). absmax 0.0 rounds 1-11.

#define M_TOT 14
#define CDIM 128
#define TAU 0.05f
#define XSTR 68        // xpose row stride in words (272 B, 16B-aligned)

// ---------------- prep: counting sort by item ----------------
__global__ void impact_hist(const int* __restrict__ item_ids,
                            int* __restrict__ hist, int B) {
    int i = blockIdx.x * blockDim.x + threadIdx.x;
    int i4 = i * 4;
    if (i4 + 3 < B) {
        int4 v = *(const int4*)(item_ids + i4);
        atomicAdd(&hist[v.x], 1);
        atomicAdd(&hist[v.y], 1);
        atomicAdd(&hist[v.z], 1);
        atomicAdd(&hist[v.w], 1);
    } else {
        for (int k = i4; k < B; ++k) atomicAdd(&hist[item_ids[k]], 1);
    }
}

__global__ __launch_bounds__(256) void impact_scan_part(
    const int* __restrict__ hist, int* __restrict__ cursor,
    int* __restrict__ bsum, int n) {
    __shared__ int sd[256];
    int t = threadIdx.x;
    int k = blockIdx.x * 256 + t;
    int v = (k < n) ? hist[k] : 0;
    sd[t] = v;
    __syncthreads();
#pragma unroll
    for (int off = 1; off < 256; off <<= 1) {
        int x = (t >= off) ? sd[t - off] : 0;
        __syncthreads();
        sd[t] += x;
        __syncthreads();
    }
    if (k < n) cursor[k] = sd[t] - v;          // exclusive within chunk
    if (t == 255) bsum[blockIdx.x] = sd[255];  // chunk total
}

// scatter with fused top-level scan of bsum (nblk <= 128)
__global__ __launch_bounds__(256) void impact_scatter(
    const int* __restrict__ item_ids,
    const int* __restrict__ user_ids,
    const int* __restrict__ nb_mod,
    int* __restrict__ cursor,
    const int* __restrict__ bsum, int nblk,
    int4* __restrict__ s4, int B)
{
    __shared__ int bo[128];
    int t = threadIdx.x;
    int v0 = 0;
    if (t < 128) {
        v0 = (t < nblk) ? bsum[t] : 0;
        bo[t] = v0;
    }
    __syncthreads();
#pragma unroll
    for (int off = 1; off < 128; off <<= 1) {
        int x = (t < 128 && t >= off) ? bo[t - off] : 0;
        __syncthreads();
        if (t < 128) bo[t] += x;
        __syncthreads();
    }
    int ex = (t < 128) ? bo[t] - v0 : 0;       // exclusive chunk offset
    __syncthreads();
    if (t < 128) bo[t] = ex;
    __syncthreads();

    int i = blockIdx.x * blockDim.x + t;
    int i4 = i * 4;
    if (i4 + 3 < B) {
        int4 it = *(const int4*)(item_ids + i4);
        int4 us = *(const int4*)(user_ids + i4);
        int n0 = nb_mod[it.x], n1 = nb_mod[it.y];
        int n2 = nb_mod[it.z], n3 = nb_mod[it.w];
        int p0 = atomicAdd(&cursor[it.x], 1) + bo[it.x >> 8];
        int p1 = atomicAdd(&cursor[it.y], 1) + bo[it.y >> 8];
        int p2 = atomicAdd(&cursor[it.z], 1) + bo[it.z >> 8];
        int p3 = atomicAdd(&cursor[it.w], 1) + bo[it.w >> 8];
        s4[p0] = make_int4(i4,     us.x, it.x, n0);
        s4[p1] = make_int4(i4 + 1, us.y, it.y, n1);
        s4[p2] = make_int4(i4 + 2, us.z, it.z, n2);
        s4[p3] = make_int4(i4 + 3, us.w, it.w, n3);
    } else {
        for (int k = i4; k < B; ++k) {
            int it = item_ids[k];
            int p = atomicAdd(&cursor[it], 1) + bo[it >> 8];
            s4[p] = make_int4(k, user_ids[k], it, nb_mod[it]);
        }
    }
}

// ---------------- main kernel ----------------
__global__ void impact_main(
    const int4* __restrict__ s4,           // sorted (q,uid,iid,nb); may be null
    const int* __restrict__ user_ids,
    const int* __restrict__ item_ids,
    const int* __restrict__ nb_mod,
    const float* __restrict__ users_emb,   // [USER_N, 128]
    const float* __restrict__ item_emb,    // [ITEM_N*14, 128]
    float* __restrict__ out,
    int B)
{
    // wave-private transpose scratch: 12 rows x 64 lanes, stride 68 words
    __shared__ float xpose[4 * 12 * XSTR];

    // chunked XCD mapping: consecutive sorted blocks -> same XCD L2
    int p = blockIdx.x;
    int lb = p;
    if ((gridDim.x & 7) == 0) {
        int cpx = gridDim.x >> 3;
        lb = (p & 7) * cpx + (p >> 3);
    }

    int w = threadIdx.x >> 6;          // wave 0..3
    int g = (threadIdx.x >> 4) & 3;    // 16-lane group in wave
    int l = threadIdx.x & 15;
    int qi = lb * 16 + w * 4 + g;      // 16 queries per block

    bool vq = qi < B;
    int4 cur;
    if (s4) {
        cur = vq ? s4[qi] : make_int4(0, 0, 0, 2);
    } else {
        int qq = vq ? qi : 0;
        int ii = item_ids[qq];
        cur = make_int4(qq, user_ids[qq], ii, nb_mod[ii]);
    }
    int q = cur.x, uid = cur.y, iid = cur.z, nb = cur.w;

    const float4* urow = (const float4*)(users_emb + (size_t)uid * CDIM);
    float4 u0 = urow[l];
    float4 u1 = urow[l + 16];
    const float4* vbase =
        (const float4*)(item_emb + ((size_t)iid * M_TOT + 1) * CDIM);
    float* X = xpose + w * 12 * XSTR;

    // wave-uniform row-count cap: sorted adjacency -> the wave's 4 groups
    // almost always share one item, so these branches are uniform & cheap
    int nbw = max(nb, __shfl_xor(nb, 16));
    nbw = max(nbw, __shfl_xor(nbw, 32));

    // batch 0 (rows 0-3): nb >= 2 always
    {
        float4 a[4], b[4];
#pragma unroll
        for (int j = 0; j < 4; ++j) {
            if (j < nb) {
                const float4* vr = vbase + (size_t)j * (CDIM / 4);
                a[j] = vr[l];
                b[j] = vr[l + 16];
            }
        }
#pragma unroll
        for (int j = 0; j < 4; ++j) {
            if (j < nb) {
                float d0 = u0.x - a[j].x, d1 = u0.y - a[j].y;
                float d2 = u0.z - a[j].z, d3 = u0.w - a[j].w;
                float d4 = u1.x - b[j].x, d5 = u1.y - b[j].y;
                float d6 = u1.z - b[j].z, d7 = u1.w - b[j].w;
                X[j * XSTR + g * 16 + l] =
                    ((d0 * d0 + d1 * d1) + (d2 * d2 + d3 * d3))
                  + ((d4 * d4 + d5 * d5) + (d6 * d6 + d7 * d7));
            }
        }
    }
    if (nbw > 4) {                     // batch 1 (rows 4-7)
        float4 a[4], b[4];
#pragma unroll
        for (int j = 0; j < 4; ++j) {
            int m = 4 + j;
            if (m < nb) {
                const float4* vr = vbase + (size_t)m * (CDIM / 4);
                a[j] = vr[l];
                b[j] = vr[l + 16];
            }
        }
#pragma unroll
        for (int j = 0; j < 4; ++j) {
            int m = 4 + j;
            if (m < nb) {
                float d0 = u0.x - a[j].x, d1 = u0.y - a[j].y;
                float d2 = u0.z - a[j].z, d3 = u0.w - a[j].w;
                float d4 = u1.x - b[j].x, d5 = u1.y - b[j].y;
                float d6 = u1.z - b[j].z, d7 = u1.w - b[j].w;
                X[m * XSTR + g * 16 + l] =
                    ((d0 * d0 + d1 * d1) + (d2 * d2 + d3 * d3))
                  + ((d4 * d4 + d5 * d5) + (d6 * d6 + d7 * d7));
            }
        }
    }
    if (nbw > 8) {                     // batch 2 (rows 8-11)
        float4 a[4], b[4];
#pragma unroll
        for (int j = 0; j < 4; ++j) {
            int m = 8 + j;
            if (m < nb) {
                const float4* vr = vbase + (size_t)m * (CDIM / 4);
                a[j] = vr[l];
                b[j] = vr[l + 16];
            }
        }
#pragma unroll
        for (int j = 0; j < 4; ++j) {
            int m = 8 + j;
            if (m < nb) {
                float d0 = u0.x - a[j].x, d1 = u0.y - a[j].y;
                float d2 = u0.z - a[j].z, d3 = u0.w - a[j].w;
                float d4 = u1.x - b[j].x, d5 = u1.y - b[j].y;
                float d6 = u1.z - b[j].z, d7 = u1.w - b[j].w;
                X[m * XSTR + g * 16 + l] =
                    ((d0 * d0 + d1 * d1) + (d2 * d2 + d3 * d3))
                  + ((d4 * d4 + d5 * d5) + (d6 * d6 + d7 * d7));
            }
        }
    }

    // X is wave-private: program order + compiler lgkmcnt orders the RAW
    // within the wave; no block barrier (validated R7-R11, absmax 0.0).
    // Rows in [nb, nbw) hold garbage for this group's column -> masked
    // below by l >= nb before the butterfly.

    // lane m reads row m's 16 partials as 4x ds_read_b128, serial f32 sum
    int lm = (l < 12) ? l : 0;
    const float4* R4 = (const float4*)(xpose + w * 12 * XSTR + lm * XSTR + g * 16);
    float4 r0 = R4[0], r1 = R4[1], r2 = R4[2], r3 = R4[3];
    float t0 = r0.x + r0.y + r0.z + r0.w;
    float t1 = r1.x + r1.y + r1.z + r1.w;
    float t2 = r2.x + r2.y + r2.z + r2.w;
    float t3 = r3.x + r3.y + r3.z + r3.w;
    float s = (t0 + t1) + (t2 + t3);
    if (l >= nb) s = INFINITY;

    // 16-lane argmin butterfly tracking (best, idx, second-best)
    float b1 = s, b2 = INFINITY;
    int i1 = l + 1;
#pragma unroll
    for (int off = 1; off < 16; off <<= 1) {
        float ob1 = __shfl_xor(b1, off);
        float ob2 = __shfl_xor(b2, off);
        int   oi1 = __shfl_xor(i1, off);
        float lo = fminf(b1, ob1);
        float hi = fmaxf(b1, ob1);
        if (ob1 < b1 || (ob1 == b1 && oi1 < i1)) i1 = oi1;
        b1 = lo;
        b2 = fminf(fminf(b2, ob2), hi);
    }

    int idx = i1;
    // near-tie (group-uniform after butterfly): exact f64 re-solve inline
    // (R1's proven reduction; v-rows are L1-hot). Rare: f32 error ~1e-4.
    if (vq && (b2 - b1 < TAU)) {
        double best = 1e300;
        int bidx = 1;
        for (int m = 1; m <= nb; ++m) {
            const float4* vr = vbase + (size_t)(m - 1) * (CDIM / 4);
            float4 v0 = vr[l];
            float4 v1 = vr[l + 16];
            float d;
            double sd = 0.0;
            d = u0.x - v0.x; sd += (double)d * d;
            d = u0.y - v0.y; sd += (double)d * d;
            d = u0.z - v0.z; sd += (double)d * d;
            d = u0.w - v0.w; sd += (double)d * d;
            d = u1.x - v1.x; sd += (double)d * d;
            d = u1.y - v1.y; sd += (double)d * d;
            d = u1.z - v1.z; sd += (double)d * d;
            d = u1.w - v1.w; sd += (double)d * d;
            sd += __shfl_xor(sd, 1);
            sd += __shfl_xor(sd, 2);
            sd += __shfl_xor(sd, 4);
            sd += __shfl_xor(sd, 8);
            if (sd < best) { best = sd; bidx = m; }
        }
        idx = bidx;
    }

    if (l == 0 && vq)
        out[q] = (float)(idx - 1) / (float)(nb - 1) + 1.0f;
}

extern "C" void kernel_launch(void* const* d_in, const int* in_sizes, int n_in,
                              void* d_out, int out_size, void* d_ws, size_t ws_size,
                              hipStream_t stream) {
    // inputs: 0 user_ids, 1 item_ids, 2 concept_ids (unused),
    //         3 users_emb_weight, 4 item_resp_emb_weight,
    //         5 mask (unused; nb_modalities carries the same info), 6 nb_modalities
    const int*   user_ids  = (const int*)d_in[0];
    const int*   item_ids  = (const int*)d_in[1];
    const float* users_emb = (const float*)d_in[3];
    const float* item_emb  = (const float*)d_in[4];
    const int*   nb_mod    = (const int*)d_in[6];
    float* out = (float*)d_out;

    int B = in_sizes[0];
    int n_items = in_sizes[6];
    int nblk = (n_items + 255) >> 8;   // scan chunks of 256

    // ws layout: s4[B] int4 | hist[n] | cursor[n] | bsum[128]
    size_t need = (size_t)B * 16 + ((size_t)n_items * 2 + 128) * 4;
    int4* s4   = (int4*)d_ws;
    int* hist  = (int*)(s4 + B);
    int* cursor = hist + n_items;
    int* bsum  = cursor + n_items;

    bool sorted = (ws_size >= need) && (nblk <= 128);
    if (sorted) {
        hipMemsetAsync(hist, 0, (size_t)n_items * sizeof(int), stream);
        impact_hist<<<(B / 4 + 255) / 256, 256, 0, stream>>>(item_ids, hist, B);
        impact_scan_part<<<nblk, 256, 0, stream>>>(hist, cursor, bsum, n_items);
        impact_scatter<<<(B / 4 + 255) / 256, 256, 0, stream>>>(
            item_ids, user_ids, nb_mod, cursor, bsum, nblk, s4, B);
    }

    int grid = (B + 15) / 16;          // 16 queries per 256-thread block
    impact_main<<<grid, 256, 0, stream>>>(
        sorted ? s4 : nullptr, user_ids, item_ids, nb_mod,
        users_emb, item_emb, out, B);
}